// Round 1
// baseline (615.341 us; speedup 1.0000x reference)
//
#include <hip/hip_runtime.h>
#include <hip/hip_bf16.h>

#define N_NODES 100000
#define N_EDGES 3200000
#define D_HID 32

// ---------------- workspace layout ----------------
// [0,40)        double stats[5]   (zeroed)
// [64,68)       int flag (is64)
// [256, 256+400000)   int degcnt[N]  (zeroed)
// [400384, +400000)   float dinv[N]
// [800512, +12800000) float h2[N*32]
// [13600512, +12800000) float agg[N*32]
// total ~26.4 MB

__global__ void detect_kernel(const void* __restrict__ ei, int* __restrict__ flag) {
    if (threadIdx.x == 0) {
        const int* p = (const int*)ei;
        int all0 = 1;
        for (int i = 0; i < 64; i++) {
            if (p[2 * i + 1] != 0) { all0 = 0; break; }
        }
        *flag = all0;  // 1 => buffer is int64 [2,E]; 0 => int32
    }
}

__global__ void stats_kernel(const float* __restrict__ x, double* __restrict__ stats) {
    double a0 = 0, a1 = 0, a2 = 0, a3 = 0, a4 = 0;
    for (int n = blockIdx.x * blockDim.x + threadIdx.x; n < N_NODES;
         n += gridDim.x * blockDim.x) {
        float2 v = ((const float2*)x)[n];
        double x0 = v.x, x1 = v.y;
        a0 += x0; a1 += x1; a2 += x0 * x0; a3 += x1 * x1; a4 += x0 * x1;
    }
    for (int off = 32; off; off >>= 1) {
        a0 += __shfl_down(a0, off);
        a1 += __shfl_down(a1, off);
        a2 += __shfl_down(a2, off);
        a3 += __shfl_down(a3, off);
        a4 += __shfl_down(a4, off);
    }
    __shared__ double sh[5][4];
    int w = threadIdx.x >> 6;
    if ((threadIdx.x & 63) == 0) {
        sh[0][w] = a0; sh[1][w] = a1; sh[2][w] = a2; sh[3][w] = a3; sh[4][w] = a4;
    }
    __syncthreads();
    if (threadIdx.x == 0) {
        double t0 = 0, t1 = 0, t2 = 0, t3 = 0, t4 = 0;
        int nw = blockDim.x >> 6;
        for (int i = 0; i < nw; i++) {
            t0 += sh[0][i]; t1 += sh[1][i]; t2 += sh[2][i]; t3 += sh[3][i]; t4 += sh[4][i];
        }
        atomicAdd(&stats[0], t0);
        atomicAdd(&stats[1], t1);
        atomicAdd(&stats[2], t2);
        atomicAdd(&stats[3], t3);
        atomicAdd(&stats[4], t4);
    }
}

__global__ void deg_kernel(const void* __restrict__ ei, const int* __restrict__ flag,
                           int* __restrict__ degcnt) {
    int is64 = *flag;
    int e = blockIdx.x * blockDim.x + threadIdx.x;
    if (e < N_EDGES) {
        int d = is64 ? (int)((const long long*)ei)[N_EDGES + e]
                     : ((const int*)ei)[N_EDGES + e];
        atomicAdd(&degcnt[d], 1);
    }
}

__global__ void encoder_kernel(const float* __restrict__ x,
                               const double* __restrict__ stats,
                               const float* __restrict__ w1, const float* __restrict__ b1,
                               const float* __restrict__ gamma, const float* __restrict__ beta,
                               const float* __restrict__ prelu_a,
                               const float* __restrict__ w2, const float* __restrict__ b2,
                               const int* __restrict__ degcnt,
                               float* __restrict__ h2, float* __restrict__ dinv,
                               float* __restrict__ agg) {
    __shared__ float lw2[32][33];
    __shared__ float s_scale[32], s_shift[32];
    for (int i = threadIdx.x; i < 1024; i += blockDim.x)
        lw2[i >> 5][i & 31] = w2[i];
    if (threadIdx.x < 32) {
        int c = threadIdx.x;
        double invN = 1.0 / (double)N_NODES;
        double m0 = stats[0] * invN, m1 = stats[1] * invN;
        double e00 = stats[2] * invN, e11 = stats[3] * invN, e01 = stats[4] * invN;
        double a = w1[2 * c], b = w1[2 * c + 1], t = b1[c];
        double meanH = a * m0 + b * m1 + t;
        double eh2 = a * a * e00 + b * b * e11 + 2.0 * a * b * e01 +
                     2.0 * t * (a * m0 + b * m1) + t * t;
        double var = eh2 - meanH * meanH;
        double inv = 1.0 / sqrt(var + 1e-5);
        float sc = (float)((double)gamma[c] * inv);
        s_scale[c] = sc;
        s_shift[c] = beta[c] - (float)meanH * sc;
    }
    __syncthreads();
    int tid = blockIdx.x * blockDim.x + threadIdx.x;  // exactly N*32 threads
    int n = tid >> 5, c = tid & 31;
    float a = w1[2 * c], b = w1[2 * c + 1], t = b1[c];
    float2 xv = ((const float2*)x)[n];
    float h1 = a * xv.x + b * xv.y + t;
    float hb = h1 * s_scale[c] + s_shift[c];
    float alpha = prelu_a[0];
    float p = hb >= 0.f ? hb : alpha * hb;
    float acc = b2[c];
#pragma unroll
    for (int k = 0; k < 32; k++)
        acc += lw2[c][k] * __shfl(p, k, 32);
    h2[tid] = acc;
    float di = 0.f;
    if (c == 0) {
        di = rsqrtf((float)degcnt[n] + 1.0f);
        dinv[n] = di;
    }
    di = __shfl(di, 0, 32);
    agg[tid] = acc * di * di;
}

__global__ void scatter_kernel(const void* __restrict__ ei, const int* __restrict__ flag,
                               const float* __restrict__ h2, const float* __restrict__ dinv,
                               float* __restrict__ agg) {
    int is64 = *flag;
    int c = threadIdx.x & 31;
    int stride = gridDim.x * blockDim.x;
    for (int t = blockIdx.x * blockDim.x + threadIdx.x; t < N_EDGES * 32; t += stride) {
        int e = t >> 5;
        int s, d;
        if (is64) {
            s = (int)((const long long*)ei)[e];
            d = (int)((const long long*)ei)[N_EDGES + e];
        } else {
            s = ((const int*)ei)[e];
            d = ((const int*)ei)[N_EDGES + e];
        }
        float en = dinv[s] * dinv[d];
        float val = h2[s * 32 + c] * en;
        unsafeAtomicAdd(&agg[d * 32 + c], val);
    }
}

__global__ void head_kernel(const float* __restrict__ agg,
                            const float* __restrict__ gcn_w, const float* __restrict__ gcn_b,
                            const float* __restrict__ wb, const float* __restrict__ bb,
                            float* __restrict__ out) {
    __shared__ float sv[32];
    __shared__ float scc;
    if (threadIdx.x < 32) {
        int c = threadIdx.x;
        float acc = 0.f;
        for (int j = 0; j < 32; j++) acc += wb[j] * gcn_w[j * 32 + c];
        sv[c] = acc;
        if (c == 0) {
            float cc = bb[0];
            for (int j = 0; j < 32; j++) cc += wb[j] * gcn_b[j];
            scc = cc;
        }
    }
    __syncthreads();
    int tid = blockIdx.x * blockDim.x + threadIdx.x;  // exactly N*32 threads
    int c = tid & 31;
    float val = agg[tid] * sv[c];
    for (int off = 16; off; off >>= 1) val += __shfl_down(val, off, 32);
    if (c == 0) out[tid >> 5] = val + scc;
}

extern "C" void kernel_launch(void* const* d_in, const int* in_sizes, int n_in,
                              void* d_out, int out_size, void* d_ws, size_t ws_size,
                              hipStream_t stream) {
    const float* x       = (const float*)d_in[0];
    const void*  ei      = d_in[1];
    const float* w1      = (const float*)d_in[2];
    const float* b1      = (const float*)d_in[3];
    const float* bn_g    = (const float*)d_in[4];
    const float* bn_b    = (const float*)d_in[5];
    const float* prelu_a = (const float*)d_in[6];
    const float* w2      = (const float*)d_in[7];
    const float* b2      = (const float*)d_in[8];
    const float* gcn_w   = (const float*)d_in[9];
    const float* gcn_b   = (const float*)d_in[10];
    const float* wb      = (const float*)d_in[11];
    const float* bb      = (const float*)d_in[12];
    float* out = (float*)d_out;

    char* base = (char*)d_ws;
    double* stats = (double*)base;
    int* flag     = (int*)(base + 64);
    int* degcnt   = (int*)(base + 256);
    float* dinv   = (float*)(base + 400384);
    float* h2     = (float*)(base + 800512);
    float* agg    = (float*)(base + 13600512);

    // zero stats + flag + degcnt in one shot
    hipMemsetAsync(d_ws, 0, 400640, stream);

    detect_kernel<<<1, 64, 0, stream>>>(ei, flag);
    stats_kernel<<<391, 256, 0, stream>>>(x, stats);
    deg_kernel<<<(N_EDGES + 255) / 256, 256, 0, stream>>>(ei, flag, degcnt);
    encoder_kernel<<<(N_NODES * 32) / 256, 256, 0, stream>>>(
        x, stats, w1, b1, bn_g, bn_b, prelu_a, w2, b2, degcnt, h2, dinv, agg);
    scatter_kernel<<<16384, 256, 0, stream>>>(ei, flag, h2, dinv, agg);
    head_kernel<<<(N_NODES * 32) / 256, 256, 0, stream>>>(agg, gcn_w, gcn_b, wb, bb, out);
}

// Round 2
// 593.805 us; speedup vs baseline: 1.0363x; 1.0363x over previous
//
#include <hip/hip_runtime.h>
#include <hip/hip_bf16.h>

#define N_NODES 100000
#define N_EDGES 3200000

// ---------------- workspace layout (bytes) ----------------
#define OFF_STATS    0        // double[5]        (zeroed)
#define OFF_FLAG     64       // int
#define OFF_HEAD     128      // float[33]  sv[32] + scc
#define OFF_PART     512      // int[32]   scan block partials
#define OFF_PSCAN    640      // int[32]   scanned partials
#define OFF_DEG      1024     // int[100000]      (zeroed)
#define OFF_RP       401024   // int[100000]  row_ptr (becomes row_end after fill)
#define OFF_DINV     801024   // float[100000]
#define OFF_HS       1201024  // float[N*32]  h2 * dinv  (12.8 MB)
#define OFF_CSR      14001024 // int[N_EDGES] src sorted by dst (12.8 MB)
// total ~26.8 MB

#define SCAN_BLOCKS 25
#define SCAN_T      256
#define SCAN_E      16   // elems per thread -> 4096 per block, 25*4096 = 102400 >= N

// ---- stats (+ int64 detect in wave 0 of block 0) ----
__global__ void stats_detect_kernel(const float* __restrict__ x, const void* __restrict__ ei,
                                    double* __restrict__ stats, int* __restrict__ flag) {
    if (blockIdx.x == 0 && threadIdx.x < 64) {
        const int* p = (const int*)ei;
        int hi = p[2 * threadIdx.x + 1];
        unsigned long long m = __ballot(hi != 0);
        if (threadIdx.x == 0) *flag = (m == 0ull) ? 1 : 0;
    }
    double a0 = 0, a1 = 0, a2 = 0, a3 = 0, a4 = 0;
    for (int n = blockIdx.x * blockDim.x + threadIdx.x; n < N_NODES;
         n += gridDim.x * blockDim.x) {
        float2 v = ((const float2*)x)[n];
        double x0 = v.x, x1 = v.y;
        a0 += x0; a1 += x1; a2 += x0 * x0; a3 += x1 * x1; a4 += x0 * x1;
    }
    for (int off = 32; off; off >>= 1) {
        a0 += __shfl_down(a0, off);
        a1 += __shfl_down(a1, off);
        a2 += __shfl_down(a2, off);
        a3 += __shfl_down(a3, off);
        a4 += __shfl_down(a4, off);
    }
    __shared__ double sh[5][4];
    int w = threadIdx.x >> 6;
    if ((threadIdx.x & 63) == 0) {
        sh[0][w] = a0; sh[1][w] = a1; sh[2][w] = a2; sh[3][w] = a3; sh[4][w] = a4;
    }
    __syncthreads();
    if (threadIdx.x == 0) {
        double t0 = 0, t1 = 0, t2 = 0, t3 = 0, t4 = 0;
        int nw = blockDim.x >> 6;
        for (int i = 0; i < nw; i++) {
            t0 += sh[0][i]; t1 += sh[1][i]; t2 += sh[2][i]; t3 += sh[3][i]; t4 += sh[4][i];
        }
        atomicAdd(&stats[0], t0);
        atomicAdd(&stats[1], t1);
        atomicAdd(&stats[2], t2);
        atomicAdd(&stats[3], t3);
        atomicAdd(&stats[4], t4);
    }
}

__global__ void deg_kernel(const void* __restrict__ ei, const int* __restrict__ flag,
                           int* __restrict__ degcnt) {
    int is64 = *flag;
    int e = blockIdx.x * blockDim.x + threadIdx.x;
    if (e < N_EDGES) {
        int d = is64 ? (int)((const long long*)ei)[N_EDGES + e]
                     : ((const int*)ei)[N_EDGES + e];
        atomicAdd(&degcnt[d], 1);
    }
}

// ---- scan stage 1: per-block sums of deg ----
__global__ void scan1_kernel(const int* __restrict__ deg, int* __restrict__ partial) {
    int b = blockIdx.x, t = threadIdx.x;
    int base = b * (SCAN_T * SCAN_E) + t * SCAN_E;
    int s = 0;
#pragma unroll
    for (int k = 0; k < SCAN_E; k++) {
        int i = base + k;
        if (i < N_NODES) s += deg[i];
    }
    __shared__ int sh[SCAN_T];
    sh[t] = s;
    __syncthreads();
    for (int off = SCAN_T / 2; off; off >>= 1) {
        if (t < off) sh[t] += sh[t + off];
        __syncthreads();
    }
    if (t == 0) partial[b] = sh[0];
}

// ---- scan stage 2 (1 block): scan partials + precompute fused head constants ----
__global__ void scan2_kernel(const int* __restrict__ partial, int* __restrict__ pscan,
                             const float* __restrict__ gcn_w, const float* __restrict__ gcn_b,
                             const float* __restrict__ wb, const float* __restrict__ bb,
                             float* __restrict__ head) {
    int t = threadIdx.x;
    if (t < 32) {
        float acc = 0.f;
        for (int j = 0; j < 32; j++) acc += wb[j] * gcn_w[j * 32 + t];
        head[t] = acc;
    }
    if (t == 0) {
        float cc = bb[0];
        for (int j = 0; j < 32; j++) cc += wb[j] * gcn_b[j];
        head[32] = cc;
        int run = 0;
        for (int b = 0; b < SCAN_BLOCKS; b++) {
            pscan[b] = run;
            run += partial[b];
        }
    }
}

// ---- scan stage 3 (blocks 0..24) fused with encoder (blocks 25..) ----
__global__ void scan3_encoder_kernel(const int* __restrict__ deg, const int* __restrict__ pscan,
                                     int* __restrict__ rp,
                                     const float* __restrict__ x,
                                     const double* __restrict__ stats,
                                     const float* __restrict__ w1, const float* __restrict__ b1,
                                     const float* __restrict__ gamma, const float* __restrict__ beta,
                                     const float* __restrict__ prelu_a,
                                     const float* __restrict__ w2, const float* __restrict__ b2,
                                     float* __restrict__ hs, float* __restrict__ dinv) {
    __shared__ int sh_scan[SCAN_T];
    __shared__ float lw2[32][33];
    __shared__ float s_scale[32], s_shift[32];

    if (blockIdx.x < SCAN_BLOCKS) {
        int b = blockIdx.x, t = threadIdx.x;
        int base = b * (SCAN_T * SCAN_E) + t * SCAN_E;
        int mysum = 0;
#pragma unroll
        for (int k = 0; k < SCAN_E; k++) {
            int i = base + k;
            if (i < N_NODES) mysum += deg[i];
        }
        sh_scan[t] = mysum;
        __syncthreads();
        for (int off = 1; off < SCAN_T; off <<= 1) {
            int v = 0;
            if (t >= off) v = sh_scan[t - off];
            __syncthreads();
            sh_scan[t] += v;
            __syncthreads();
        }
        int run = pscan[b] + sh_scan[t] - mysum;  // exclusive prefix for this thread
        for (int k = 0; k < SCAN_E; k++) {
            int i = base + k;
            if (i < N_NODES) {
                rp[i] = run;
                run += deg[i];
            }
        }
        return;
    }

    // ---------- encoder role ----------
    for (int i = threadIdx.x; i < 1024; i += blockDim.x)
        lw2[i >> 5][i & 31] = w2[i];
    if (threadIdx.x < 32) {
        int c = threadIdx.x;
        double invN = 1.0 / (double)N_NODES;
        double m0 = stats[0] * invN, m1 = stats[1] * invN;
        double e00 = stats[2] * invN, e11 = stats[3] * invN, e01 = stats[4] * invN;
        double a = w1[2 * c], b = w1[2 * c + 1], t = b1[c];
        double meanH = a * m0 + b * m1 + t;
        double eh2 = a * a * e00 + b * b * e11 + 2.0 * a * b * e01 +
                     2.0 * t * (a * m0 + b * m1) + t * t;
        double var = eh2 - meanH * meanH;
        double inv = 1.0 / sqrt(var + 1e-5);
        float sc = (float)((double)gamma[c] * inv);
        s_scale[c] = sc;
        s_shift[c] = beta[c] - (float)meanH * sc;
    }
    __syncthreads();
    int tid = (blockIdx.x - SCAN_BLOCKS) * blockDim.x + threadIdx.x;  // exactly N*32
    int n = tid >> 5, c = tid & 31;
    float a = w1[2 * c], b = w1[2 * c + 1], t = b1[c];
    float2 xv = ((const float2*)x)[n];
    float h1 = a * xv.x + b * xv.y + t;
    float hb = h1 * s_scale[c] + s_shift[c];
    float alpha = prelu_a[0];
    float p = hb >= 0.f ? hb : alpha * hb;
    float acc = b2[c];
#pragma unroll
    for (int k = 0; k < 32; k++)
        acc += lw2[c][k] * __shfl(p, k, 32);
    float di = 0.f;
    if (c == 0) {
        di = rsqrtf((float)deg[n] + 1.0f);
        dinv[n] = di;
    }
    di = __shfl(di, 0, 32);
    hs[tid] = acc * di;  // pre-scaled by dinv[src]
}

// ---- fill CSR: bump row_ptr (start recovered later from rp[d-1]) ----
__global__ void fill_kernel(const void* __restrict__ ei, const int* __restrict__ flag,
                            int* __restrict__ rp, int* __restrict__ csr) {
    int is64 = *flag;
    int e = blockIdx.x * blockDim.x + threadIdx.x;
    if (e < N_EDGES) {
        int s, d;
        if (is64) {
            s = (int)((const long long*)ei)[e];
            d = (int)((const long long*)ei)[N_EDGES + e];
        } else {
            s = ((const int*)ei)[e];
            d = ((const int*)ei)[N_EDGES + e];
        }
        int pos = atomicAdd(&rp[d], 1);
        csr[pos] = s;
    }
}

// ---- gather-aggregate fused with GCN linear + score head ----
__global__ void aggregate_kernel(const int* __restrict__ rp, const int* __restrict__ csr,
                                 const float* __restrict__ hs, const float* __restrict__ dinv,
                                 const float* __restrict__ head, float* __restrict__ out) {
    __shared__ float sv[32];
    __shared__ float sccs;
    if (threadIdx.x < 32) sv[threadIdx.x] = head[threadIdx.x];
    if (threadIdx.x == 0) sccs = head[32];
    __syncthreads();

    int g = blockIdx.x * blockDim.x + threadIdx.x;  // exactly N*32
    int node = g >> 5, c = g & 31;
    float acc = hs[g];  // self-loop term (hs[d]; final *dinv[d] applied below)
    int row0 = node ? rp[node - 1] : 0;  // after fill, rp[d] == original row_ptr[d+1]
    int row1 = rp[node];
    for (int base = row0; base < row1; base += 32) {
        int nleft = row1 - base;
        int sl = 0;
        if (c < nleft) sl = csr[base + c];
        int cnt = nleft < 32 ? nleft : 32;
        int j = 0;
        for (; j + 8 <= cnt; j += 8) {
#pragma unroll
            for (int u = 0; u < 8; u++) {
                int s = __shfl(sl, j + u, 32);
                acc += hs[s * 32 + c];
            }
        }
        for (; j < cnt; j++) {
            int s = __shfl(sl, j, 32);
            acc += hs[s * 32 + c];
        }
    }
    acc *= dinv[node];
    float val = acc * sv[c];
    for (int off = 16; off; off >>= 1) val += __shfl_down(val, off, 32);
    if (c == 0) out[node] = val + sccs;
}

extern "C" void kernel_launch(void* const* d_in, const int* in_sizes, int n_in,
                              void* d_out, int out_size, void* d_ws, size_t ws_size,
                              hipStream_t stream) {
    const float* x       = (const float*)d_in[0];
    const void*  ei      = d_in[1];
    const float* w1      = (const float*)d_in[2];
    const float* b1      = (const float*)d_in[3];
    const float* bn_g    = (const float*)d_in[4];
    const float* bn_b    = (const float*)d_in[5];
    const float* prelu_a = (const float*)d_in[6];
    const float* w2      = (const float*)d_in[7];
    const float* b2      = (const float*)d_in[8];
    const float* gcn_w   = (const float*)d_in[9];
    const float* gcn_b   = (const float*)d_in[10];
    const float* wb      = (const float*)d_in[11];
    const float* bb      = (const float*)d_in[12];
    float* out = (float*)d_out;

    char* base = (char*)d_ws;
    double* stats = (double*)(base + OFF_STATS);
    int*    flag  = (int*)(base + OFF_FLAG);
    float*  head  = (float*)(base + OFF_HEAD);
    int*    part  = (int*)(base + OFF_PART);
    int*    pscan = (int*)(base + OFF_PSCAN);
    int*    deg   = (int*)(base + OFF_DEG);
    int*    rp    = (int*)(base + OFF_RP);
    float*  dinv  = (float*)(base + OFF_DINV);
    float*  hs    = (float*)(base + OFF_HS);
    int*    csr   = (int*)(base + OFF_CSR);

    // zero stats + flag + deg in one shot
    hipMemsetAsync(d_ws, 0, OFF_DEG + N_NODES * 4, stream);

    stats_detect_kernel<<<391, 256, 0, stream>>>(x, ei, stats, flag);
    deg_kernel<<<(N_EDGES + 255) / 256, 256, 0, stream>>>(ei, flag, deg);
    scan1_kernel<<<SCAN_BLOCKS, SCAN_T, 0, stream>>>(deg, part);
    scan2_kernel<<<1, 64, 0, stream>>>(part, pscan, gcn_w, gcn_b, wb, bb, head);
    scan3_encoder_kernel<<<SCAN_BLOCKS + (N_NODES * 32) / 256, 256, 0, stream>>>(
        deg, pscan, rp, x, stats, w1, b1, bn_g, bn_b, prelu_a, w2, b2, hs, dinv);
    fill_kernel<<<(N_EDGES + 255) / 256, 256, 0, stream>>>(ei, flag, rp, csr);
    aggregate_kernel<<<(N_NODES * 32) / 256, 256, 0, stream>>>(rp, csr, hs, dinv, head, out);
}

// Round 3
// 452.838 us; speedup vs baseline: 1.3589x; 1.3113x over previous
//
#include <hip/hip_runtime.h>
#include <hip/hip_bf16.h>

#define N_NODES 100000
#define N_EDGES 3200000

// ---------------- workspace layout (bytes) ----------------
#define OFF_STATS 0        // double[5]   (zeroed)
#define OFF_DEG   1024     // float[N]    (zeroed)
#define OFF_ACC   401024   // float[N]    (zeroed)
#define OFF_DINV  801024   // float[N]
#define OFF_GS    1201024  // float[N]
// total ~1.6 MB

#define STATS_BLOCKS 200
#define EDGE_THREADS (N_EDGES / 2)      // 2 edges per thread
#define EDGE_BLOCKS  (EDGE_THREADS / 256)  // 6250

// per-block int64-vs-int32 detection: high words of first 64 int64 slots
__device__ __forceinline__ bool detect_is64(const void* ei) {
    const int* p = (const int*)ei;
    int lane = threadIdx.x & 63;
    int hi = p[2 * lane + 1];
    unsigned long long m = __ballot(hi != 0);
    return m == 0ull;  // wave-uniform
}

// ---- fused: BN stats over x  +  f32 degree histogram ----
__global__ void stats_deg_kernel(const float* __restrict__ x, const void* __restrict__ ei,
                                 double* __restrict__ stats, float* __restrict__ degf) {
    if (blockIdx.x >= STATS_BLOCKS) {
        // ---- degree role ----
        bool is64 = detect_is64(ei);
        int tid = (blockIdx.x - STATS_BLOCKS) * blockDim.x + threadIdx.x;  // < E/2
        if (is64) {
            long2 d2 = ((const long2*)ei)[N_EDGES / 2 + tid];
            unsafeAtomicAdd(&degf[(int)d2.x], 1.0f);
            unsafeAtomicAdd(&degf[(int)d2.y], 1.0f);
        } else {
            int2 d2 = ((const int2*)ei)[N_EDGES / 2 + tid];
            unsafeAtomicAdd(&degf[d2.x], 1.0f);
            unsafeAtomicAdd(&degf[d2.y], 1.0f);
        }
        return;
    }
    // ---- stats role ----
    double a0 = 0, a1 = 0, a2 = 0, a3 = 0, a4 = 0;
    for (int n = blockIdx.x * blockDim.x + threadIdx.x; n < N_NODES;
         n += STATS_BLOCKS * blockDim.x) {
        float2 v = ((const float2*)x)[n];
        double x0 = v.x, x1 = v.y;
        a0 += x0; a1 += x1; a2 += x0 * x0; a3 += x1 * x1; a4 += x0 * x1;
    }
    for (int off = 32; off; off >>= 1) {
        a0 += __shfl_down(a0, off);
        a1 += __shfl_down(a1, off);
        a2 += __shfl_down(a2, off);
        a3 += __shfl_down(a3, off);
        a4 += __shfl_down(a4, off);
    }
    __shared__ double sh[5][4];
    int w = threadIdx.x >> 6;
    if ((threadIdx.x & 63) == 0) {
        sh[0][w] = a0; sh[1][w] = a1; sh[2][w] = a2; sh[3][w] = a3; sh[4][w] = a4;
    }
    __syncthreads();
    if (threadIdx.x == 0) {
        double t0 = 0, t1 = 0, t2 = 0, t3 = 0, t4 = 0;
        int nw = blockDim.x >> 6;
        for (int i = 0; i < nw; i++) {
            t0 += sh[0][i]; t1 += sh[1][i]; t2 += sh[2][i]; t3 += sh[3][i]; t4 += sh[4][i];
        }
        atomicAdd(&stats[0], t0);
        atomicAdd(&stats[1], t1);
        atomicAdd(&stats[2], t2);
        atomicAdd(&stats[3], t3);
        atomicAdd(&stats[4], t4);
    }
}

// ---- encoder: h2 -> g[n] = h2 . v ; gs[n] = dinv[n]*g[n]; acc init with self term ----
__global__ void encoder_kernel(const float* __restrict__ x,
                               const double* __restrict__ stats,
                               const float* __restrict__ w1, const float* __restrict__ b1,
                               const float* __restrict__ gamma, const float* __restrict__ beta,
                               const float* __restrict__ prelu_a,
                               const float* __restrict__ w2, const float* __restrict__ b2,
                               const float* __restrict__ gcn_w, const float* __restrict__ wb,
                               const float* __restrict__ degf,
                               float* __restrict__ dinv, float* __restrict__ gs,
                               float* __restrict__ acc) {
    __shared__ float lw2[32][33];
    __shared__ float s_scale[32], s_shift[32], sv[32];
    for (int i = threadIdx.x; i < 1024; i += blockDim.x)
        lw2[i >> 5][i & 31] = w2[i];
    if (threadIdx.x < 32) {
        int c = threadIdx.x;
        double invN = 1.0 / (double)N_NODES;
        double m0 = stats[0] * invN, m1 = stats[1] * invN;
        double e00 = stats[2] * invN, e11 = stats[3] * invN, e01 = stats[4] * invN;
        double a = w1[2 * c], b = w1[2 * c + 1], t = b1[c];
        double meanH = a * m0 + b * m1 + t;
        double eh2 = a * a * e00 + b * b * e11 + 2.0 * a * b * e01 +
                     2.0 * t * (a * m0 + b * m1) + t * t;
        double var = eh2 - meanH * meanH;
        double inv = 1.0 / sqrt(var + 1e-5);
        float sc = (float)((double)gamma[c] * inv);
        s_scale[c] = sc;
        s_shift[c] = beta[c] - (float)meanH * sc;
        // v = gcn_w^T wb^T
        float vc = 0.f;
        for (int j = 0; j < 32; j++) vc += wb[j] * gcn_w[j * 32 + c];
        sv[c] = vc;
    }
    __syncthreads();
    int tid = blockIdx.x * blockDim.x + threadIdx.x;  // exactly N*32 threads
    int n = tid >> 5, c = tid & 31;
    float a = w1[2 * c], b = w1[2 * c + 1], t = b1[c];
    float2 xv = ((const float2*)x)[n];
    float h1 = a * xv.x + b * xv.y + t;
    float hb = h1 * s_scale[c] + s_shift[c];
    float alpha = prelu_a[0];
    float p = hb >= 0.f ? hb : alpha * hb;
    float h2c = b2[c];
#pragma unroll
    for (int k = 0; k < 32; k++)
        h2c += lw2[c][k] * __shfl(p, k, 32);
    // g = h2 . v, reduced across the 32-lane half-wave
    float val = h2c * sv[c];
    for (int off = 16; off; off >>= 1) val += __shfl_down(val, off, 32);
    if (c == 0) {
        float di = rsqrtf(degf[n] + 1.0f);
        float g = di * val;   // gs = dinv * g
        dinv[n] = di;
        gs[n] = g;
        acc[n] = g;           // self-loop term: dinv^2*gval = dinv*gs, applied in finalize
    }
}

// ---- edge scatter: acc[dst] += gs[src]  (scalar, fire-and-forget) ----
__global__ void scatter_kernel(const void* __restrict__ ei, const float* __restrict__ gs,
                               float* __restrict__ acc) {
    bool is64 = detect_is64(ei);
    int tid = blockIdx.x * blockDim.x + threadIdx.x;  // < E/2
    if (is64) {
        long2 s2 = ((const long2*)ei)[tid];
        long2 d2 = ((const long2*)ei)[N_EDGES / 2 + tid];
        float v0 = gs[(int)s2.x];
        float v1 = gs[(int)s2.y];
        unsafeAtomicAdd(&acc[(int)d2.x], v0);
        unsafeAtomicAdd(&acc[(int)d2.y], v1);
    } else {
        int2 s2 = ((const int2*)ei)[tid];
        int2 d2 = ((const int2*)ei)[N_EDGES / 2 + tid];
        float v0 = gs[s2.x];
        float v1 = gs[s2.y];
        unsafeAtomicAdd(&acc[d2.x], v0);
        unsafeAtomicAdd(&acc[d2.y], v1);
    }
}

// ---- finalize: out = dinv*acc + const ----
__global__ void finalize_kernel(const float* __restrict__ dinv, const float* __restrict__ acc,
                                const float* __restrict__ gcn_b, const float* __restrict__ wb,
                                const float* __restrict__ bb, float* __restrict__ out) {
    __shared__ float scc;
    if (threadIdx.x < 32) {
        float pv = wb[threadIdx.x] * gcn_b[threadIdx.x];
        for (int off = 16; off; off >>= 1) pv += __shfl_down(pv, off, 32);
        if (threadIdx.x == 0) scc = pv + bb[0];
    }
    __syncthreads();
    int n = blockIdx.x * blockDim.x + threadIdx.x;
    if (n < N_NODES) out[n] = dinv[n] * acc[n] + scc;
}

extern "C" void kernel_launch(void* const* d_in, const int* in_sizes, int n_in,
                              void* d_out, int out_size, void* d_ws, size_t ws_size,
                              hipStream_t stream) {
    const float* x       = (const float*)d_in[0];
    const void*  ei      = d_in[1];
    const float* w1      = (const float*)d_in[2];
    const float* b1      = (const float*)d_in[3];
    const float* bn_g    = (const float*)d_in[4];
    const float* bn_b    = (const float*)d_in[5];
    const float* prelu_a = (const float*)d_in[6];
    const float* w2      = (const float*)d_in[7];
    const float* b2      = (const float*)d_in[8];
    const float* gcn_w   = (const float*)d_in[9];
    const float* gcn_b   = (const float*)d_in[10];
    const float* wb      = (const float*)d_in[11];
    const float* bb      = (const float*)d_in[12];
    float* out = (float*)d_out;

    char* base = (char*)d_ws;
    double* stats = (double*)(base + OFF_STATS);
    float*  degf  = (float*)(base + OFF_DEG);
    float*  acc   = (float*)(base + OFF_ACC);
    float*  dinv  = (float*)(base + OFF_DINV);
    float*  gs    = (float*)(base + OFF_GS);

    // zero stats + degf + acc
    hipMemsetAsync(d_ws, 0, OFF_ACC + N_NODES * 4, stream);

    stats_deg_kernel<<<STATS_BLOCKS + EDGE_BLOCKS, 256, 0, stream>>>(x, ei, stats, degf);
    encoder_kernel<<<(N_NODES * 32) / 256, 256, 0, stream>>>(
        x, stats, w1, b1, bn_g, bn_b, prelu_a, w2, b2, gcn_w, wb, degf, dinv, gs, acc);
    scatter_kernel<<<EDGE_BLOCKS, 256, 0, stream>>>(ei, gs, acc);
    finalize_kernel<<<(N_NODES + 255) / 256, 256, 0, stream>>>(dinv, acc, gcn_b, wb, bb, out);
}

// Round 4
// 231.933 us; speedup vs baseline: 2.6531x; 1.9524x over previous
//
#include <hip/hip_runtime.h>
#include <hip/hip_bf16.h>

#define N_NODES 100000
#define N_EDGES 3200000

#define P_PARTS 4
#define PART    25600                    // 4*25600 = 102400 >= N
#define BLOCKS  256
#define SLICES  (BLOCKS / P_PARTS)       // 64
#define SLICE_E (N_EDGES / SLICES)       // 50000 exact
#define T_HIST  1024

// ---------------- workspace layout (bytes) ----------------
#define OFF_STATS 0        // double[5]   (zeroed)
#define OFF_DEG   1024     // float[102400] (zeroed)
#define OFF_ACC   410624   // float[102400]
#define OFF_DINV  1021024  // float[N]
#define OFF_GS    1421024  // float[N]
// total ~1.9 MB

// per-wave int64-vs-int32 detection: high words of first 64 int64 slots
__device__ __forceinline__ bool detect_is64(const void* ei) {
    const int* p = (const int*)ei;
    int lane = threadIdx.x & 63;
    int hi = p[2 * lane + 1];
    unsigned long long m = __ballot(hi != 0);
    return m == 0ull;  // wave-uniform
}

// ---- pass A: BN stats over x + LDS-privatized degree histogram ----
__global__ __launch_bounds__(T_HIST) void deg_stats_kernel(
        const float* __restrict__ x, const void* __restrict__ ei,
        double* __restrict__ stats, float* __restrict__ degf) {
    __shared__ float hist[PART];
    __shared__ double sh[5][16];
    bool is64 = detect_is64(ei);
    int p = blockIdx.x & (P_PARTS - 1);
    int slice = blockIdx.x >> 2;
    int base = p * PART;

    for (int i = threadIdx.x; i < PART; i += T_HIST) hist[i] = 0.f;

    // ---- stats: one node per thread (256*1024 >= N) ----
    {
        double a0 = 0, a1 = 0, a2 = 0, a3 = 0, a4 = 0;
        int n = blockIdx.x * T_HIST + threadIdx.x;
        if (n < N_NODES) {
            float2 v = ((const float2*)x)[n];
            double x0 = v.x, x1 = v.y;
            a0 = x0; a1 = x1; a2 = x0 * x0; a3 = x1 * x1; a4 = x0 * x1;
        }
        for (int off = 32; off; off >>= 1) {
            a0 += __shfl_down(a0, off);
            a1 += __shfl_down(a1, off);
            a2 += __shfl_down(a2, off);
            a3 += __shfl_down(a3, off);
            a4 += __shfl_down(a4, off);
        }
        int w = threadIdx.x >> 6;
        if ((threadIdx.x & 63) == 0) {
            sh[0][w] = a0; sh[1][w] = a1; sh[2][w] = a2; sh[3][w] = a3; sh[4][w] = a4;
        }
        __syncthreads();  // also covers hist zero-init
        if (threadIdx.x == 0) {
            double t0 = 0, t1 = 0, t2 = 0, t3 = 0, t4 = 0;
            for (int i = 0; i < 16; i++) {
                t0 += sh[0][i]; t1 += sh[1][i]; t2 += sh[2][i]; t3 += sh[3][i]; t4 += sh[4][i];
            }
            atomicAdd(&stats[0], t0);
            atomicAdd(&stats[1], t1);
            atomicAdd(&stats[2], t2);
            atomicAdd(&stats[3], t3);
            atomicAdd(&stats[4], t4);
        }
    }

    // ---- degree histogram over this block's edge slice ----
    int e0 = slice * SLICE_E, e1 = e0 + SLICE_E;
    if (is64) {
        const long long* dstp = (const long long*)ei + N_EDGES;
        for (int e = e0 + threadIdx.x; e < e1; e += T_HIST) {
            unsigned ld = (unsigned)((int)dstp[e] - base);
            if (ld < PART) atomicAdd(&hist[ld], 1.0f);
        }
    } else {
        const int* dstp = (const int*)ei + N_EDGES;
        for (int e = e0 + threadIdx.x; e < e1; e += T_HIST) {
            unsigned ld = (unsigned)(dstp[e] - base);
            if (ld < PART) atomicAdd(&hist[ld], 1.0f);
        }
    }
    __syncthreads();
    // ---- coalesced flush (skip zeros) ----
    for (int i = threadIdx.x; i < PART; i += T_HIST) {
        float v = hist[i];
        if (v != 0.f) unsafeAtomicAdd(&degf[base + i], v);
    }
}

// ---- encoder: gs[n] = dinv[n] * (h2[n] . v);  acc[n] = gs[n] (self term) ----
__global__ void encoder_kernel(const float* __restrict__ x,
                               const double* __restrict__ stats,
                               const float* __restrict__ w1, const float* __restrict__ b1,
                               const float* __restrict__ gamma, const float* __restrict__ beta,
                               const float* __restrict__ prelu_a,
                               const float* __restrict__ w2, const float* __restrict__ b2,
                               const float* __restrict__ gcn_w, const float* __restrict__ wb,
                               const float* __restrict__ degf,
                               float* __restrict__ dinv, float* __restrict__ gs,
                               float* __restrict__ acc) {
    __shared__ float lw2[32][33];
    __shared__ float s_scale[32], s_shift[32], sv[32];
    for (int i = threadIdx.x; i < 1024; i += blockDim.x)
        lw2[i >> 5][i & 31] = w2[i];
    if (threadIdx.x < 32) {
        int c = threadIdx.x;
        double invN = 1.0 / (double)N_NODES;
        double m0 = stats[0] * invN, m1 = stats[1] * invN;
        double e00 = stats[2] * invN, e11 = stats[3] * invN, e01 = stats[4] * invN;
        double a = w1[2 * c], b = w1[2 * c + 1], t = b1[c];
        double meanH = a * m0 + b * m1 + t;
        double eh2 = a * a * e00 + b * b * e11 + 2.0 * a * b * e01 +
                     2.0 * t * (a * m0 + b * m1) + t * t;
        double var = eh2 - meanH * meanH;
        double inv = 1.0 / sqrt(var + 1e-5);
        float sc = (float)((double)gamma[c] * inv);
        s_scale[c] = sc;
        s_shift[c] = beta[c] - (float)meanH * sc;
        float vc = 0.f;
        for (int j = 0; j < 32; j++) vc += wb[j] * gcn_w[j * 32 + c];
        sv[c] = vc;
    }
    __syncthreads();
    int tid = blockIdx.x * blockDim.x + threadIdx.x;  // exactly N*32 threads
    int n = tid >> 5, c = tid & 31;
    float a = w1[2 * c], b = w1[2 * c + 1], t = b1[c];
    float2 xv = ((const float2*)x)[n];
    float h1 = a * xv.x + b * xv.y + t;
    float hb = h1 * s_scale[c] + s_shift[c];
    float alpha = prelu_a[0];
    float p = hb >= 0.f ? hb : alpha * hb;
    float h2c = b2[c];
#pragma unroll
    for (int k = 0; k < 32; k++)
        h2c += lw2[c][k] * __shfl(p, k, 32);
    float val = h2c * sv[c];
    for (int off = 16; off; off >>= 1) val += __shfl_down(val, off, 32);
    if (c == 0) {
        float di = rsqrtf(degf[n] + 1.0f);
        float g = di * val;
        dinv[n] = di;
        gs[n] = g;
        acc[n] = g;  // self-loop term; finalize multiplies by dinv
    }
}

// ---- pass B: LDS-privatized scatter  acc[dst] += gs[src] ----
__global__ __launch_bounds__(T_HIST) void scatter_hist_kernel(
        const void* __restrict__ ei, const float* __restrict__ gs,
        float* __restrict__ acc) {
    __shared__ float hist[PART];
    bool is64 = detect_is64(ei);
    int p = blockIdx.x & (P_PARTS - 1);
    int slice = blockIdx.x >> 2;
    int base = p * PART;

    for (int i = threadIdx.x; i < PART; i += T_HIST) hist[i] = 0.f;
    __syncthreads();

    int e0 = slice * SLICE_E, e1 = e0 + SLICE_E;
    if (is64) {
        const long long* srcp = (const long long*)ei;
        const long long* dstp = srcp + N_EDGES;
        for (int e = e0 + threadIdx.x; e < e1; e += T_HIST) {
            unsigned ld = (unsigned)((int)dstp[e] - base);
            if (ld < PART) {
                int s = (int)srcp[e];
                atomicAdd(&hist[ld], gs[s]);
            }
        }
    } else {
        const int* srcp = (const int*)ei;
        const int* dstp = srcp + N_EDGES;
        for (int e = e0 + threadIdx.x; e < e1; e += T_HIST) {
            unsigned ld = (unsigned)(dstp[e] - base);
            if (ld < PART) {
                int s = srcp[e];
                atomicAdd(&hist[ld], gs[s]);
            }
        }
    }
    __syncthreads();
    for (int i = threadIdx.x; i < PART; i += T_HIST) {
        float v = hist[i];
        if (v != 0.f) unsafeAtomicAdd(&acc[base + i], v);
    }
}

// ---- finalize: out = dinv*acc + const ----
__global__ void finalize_kernel(const float* __restrict__ dinv, const float* __restrict__ acc,
                                const float* __restrict__ gcn_b, const float* __restrict__ wb,
                                const float* __restrict__ bb, float* __restrict__ out) {
    __shared__ float scc;
    if (threadIdx.x < 32) {
        float pv = wb[threadIdx.x] * gcn_b[threadIdx.x];
        for (int off = 16; off; off >>= 1) pv += __shfl_down(pv, off, 32);
        if (threadIdx.x == 0) scc = pv + bb[0];
    }
    __syncthreads();
    int n = blockIdx.x * blockDim.x + threadIdx.x;
    if (n < N_NODES) out[n] = dinv[n] * acc[n] + scc;
}

extern "C" void kernel_launch(void* const* d_in, const int* in_sizes, int n_in,
                              void* d_out, int out_size, void* d_ws, size_t ws_size,
                              hipStream_t stream) {
    const float* x       = (const float*)d_in[0];
    const void*  ei      = d_in[1];
    const float* w1      = (const float*)d_in[2];
    const float* b1      = (const float*)d_in[3];
    const float* bn_g    = (const float*)d_in[4];
    const float* bn_b    = (const float*)d_in[5];
    const float* prelu_a = (const float*)d_in[6];
    const float* w2      = (const float*)d_in[7];
    const float* b2      = (const float*)d_in[8];
    const float* gcn_w   = (const float*)d_in[9];
    const float* gcn_b   = (const float*)d_in[10];
    const float* wb      = (const float*)d_in[11];
    const float* bb      = (const float*)d_in[12];
    float* out = (float*)d_out;

    char* base = (char*)d_ws;
    double* stats = (double*)(base + OFF_STATS);
    float*  degf  = (float*)(base + OFF_DEG);
    float*  acc   = (float*)(base + OFF_ACC);
    float*  dinv  = (float*)(base + OFF_DINV);
    float*  gs    = (float*)(base + OFF_GS);

    // zero stats + degf
    hipMemsetAsync(d_ws, 0, OFF_DEG + PART * P_PARTS * 4, stream);

    deg_stats_kernel<<<BLOCKS, T_HIST, 0, stream>>>(x, ei, stats, degf);
    encoder_kernel<<<(N_NODES * 32) / 256, 256, 0, stream>>>(
        x, stats, w1, b1, bn_g, bn_b, prelu_a, w2, b2, gcn_w, wb, degf, dinv, gs, acc);
    scatter_hist_kernel<<<BLOCKS, T_HIST, 0, stream>>>(ei, gs, acc);
    finalize_kernel<<<(N_NODES + 255) / 256, 256, 0, stream>>>(dinv, acc, gcn_b, wb, bb, out);
}

// Round 5
// 206.790 us; speedup vs baseline: 2.9757x; 1.1216x over previous
//
#include <hip/hip_runtime.h>
#include <hip/hip_bf16.h>

#define N_NODES 100000
#define N_EDGES 3200000

#define P_PARTS 8
#define PART    12800                    // 8*12800 = 102400 >= N ; 51.2 KB LDS
#define SLICES  64
#define SLICE_E (N_EDGES / SLICES)       // 50000, %4 == 0
#define BLOCKS_H (P_PARTS * SLICES)      // 512 = 2 blocks/CU
#define T_HIST  1024

// ---------------- workspace layout (bytes) ----------------
#define OFF_STATS 0        // double[5]     (zeroed)
#define OFF_DEG   1024     // float[102400] (zeroed)
#define OFF_ACC   410624   // float[102400]
#define OFF_DINV  820224   // float[N]
#define OFF_GS    1220224  // float[N]
// total ~1.62 MB

// per-wave int64-vs-int32 detection: high words of first 64 int64 slots
__device__ __forceinline__ bool detect_is64(const void* ei) {
    const int* p = (const int*)ei;
    int lane = threadIdx.x & 63;
    int hi = p[2 * lane + 1];
    unsigned long long m = __ballot(hi != 0);
    return m == 0ull;  // wave-uniform
}

// ---- pass A: BN stats over x + LDS-privatized degree histogram ----
__global__ __launch_bounds__(T_HIST, 8) void deg_stats_kernel(
        const float* __restrict__ x, const void* __restrict__ ei,
        double* __restrict__ stats, float* __restrict__ degf) {
    __shared__ float hist[PART];
    __shared__ double sh[5][16];
    bool is64 = detect_is64(ei);
    int p = blockIdx.x & (P_PARTS - 1);
    int slice = blockIdx.x >> 3;
    int base = p * PART;

    for (int i = threadIdx.x; i < PART; i += T_HIST) hist[i] = 0.f;

    // ---- stats: one node per thread (512*1024 >= N) ----
    {
        double a0 = 0, a1 = 0, a2 = 0, a3 = 0, a4 = 0;
        int n = blockIdx.x * T_HIST + threadIdx.x;
        if (n < N_NODES) {
            float2 v = ((const float2*)x)[n];
            double x0 = v.x, x1 = v.y;
            a0 = x0; a1 = x1; a2 = x0 * x0; a3 = x1 * x1; a4 = x0 * x1;
        }
        for (int off = 32; off; off >>= 1) {
            a0 += __shfl_down(a0, off);
            a1 += __shfl_down(a1, off);
            a2 += __shfl_down(a2, off);
            a3 += __shfl_down(a3, off);
            a4 += __shfl_down(a4, off);
        }
        int w = threadIdx.x >> 6;
        if ((threadIdx.x & 63) == 0) {
            sh[0][w] = a0; sh[1][w] = a1; sh[2][w] = a2; sh[3][w] = a3; sh[4][w] = a4;
        }
        __syncthreads();  // also covers hist zero-init
        if (threadIdx.x == 0) {
            double t0 = 0, t1 = 0, t2 = 0, t3 = 0, t4 = 0;
            for (int i = 0; i < 16; i++) {
                t0 += sh[0][i]; t1 += sh[1][i]; t2 += sh[2][i]; t3 += sh[3][i]; t4 += sh[4][i];
            }
            atomicAdd(&stats[0], t0);
            atomicAdd(&stats[1], t1);
            atomicAdd(&stats[2], t2);
            atomicAdd(&stats[3], t3);
            atomicAdd(&stats[4], t4);
        }
    }

    // ---- degree histogram, 4 edges/thread/iter ----
    int e0 = slice * SLICE_E, e1 = e0 + SLICE_E;
    if (is64) {
        const long long* dstp = (const long long*)ei + N_EDGES;
        for (int e = e0 + threadIdx.x * 4; e < e1; e += T_HIST * 4) {
            longlong2 da = *(const longlong2*)(dstp + e);
            longlong2 db = *(const longlong2*)(dstp + e + 2);
            unsigned l0 = (unsigned)((int)da.x - base);
            unsigned l1 = (unsigned)((int)da.y - base);
            unsigned l2 = (unsigned)((int)db.x - base);
            unsigned l3 = (unsigned)((int)db.y - base);
            if (l0 < PART) atomicAdd(&hist[l0], 1.0f);
            if (l1 < PART) atomicAdd(&hist[l1], 1.0f);
            if (l2 < PART) atomicAdd(&hist[l2], 1.0f);
            if (l3 < PART) atomicAdd(&hist[l3], 1.0f);
        }
    } else {
        const int* dstp = (const int*)ei + N_EDGES;
        for (int e = e0 + threadIdx.x * 4; e < e1; e += T_HIST * 4) {
            int4 d4 = *(const int4*)(dstp + e);
            unsigned l0 = (unsigned)(d4.x - base);
            unsigned l1 = (unsigned)(d4.y - base);
            unsigned l2 = (unsigned)(d4.z - base);
            unsigned l3 = (unsigned)(d4.w - base);
            if (l0 < PART) atomicAdd(&hist[l0], 1.0f);
            if (l1 < PART) atomicAdd(&hist[l1], 1.0f);
            if (l2 < PART) atomicAdd(&hist[l2], 1.0f);
            if (l3 < PART) atomicAdd(&hist[l3], 1.0f);
        }
    }
    __syncthreads();
    // ---- coalesced flush (skip zeros) ----
    for (int i = threadIdx.x; i < PART; i += T_HIST) {
        float v = hist[i];
        if (v != 0.f) unsafeAtomicAdd(&degf[base + i], v);
    }
}

// ---- encoder (scalar form): gs[n] = dinv[n] * (b2.v + sum_c PReLU(A x0 + B x1 + C) u[c]) ----
__global__ void encoder_kernel(const float* __restrict__ x,
                               const double* __restrict__ stats,
                               const float* __restrict__ w1, const float* __restrict__ b1,
                               const float* __restrict__ gamma, const float* __restrict__ beta,
                               const float* __restrict__ prelu_a,
                               const float* __restrict__ w2, const float* __restrict__ b2,
                               const float* __restrict__ gcn_w, const float* __restrict__ wb,
                               const float* __restrict__ degf,
                               float* __restrict__ dinv, float* __restrict__ gs,
                               float* __restrict__ acc) {
    __shared__ float sA[32], sB[32], sC[32], sV[32], sU[32];
    __shared__ float sGB;
    if (threadIdx.x < 32) {
        int c = threadIdx.x;
        double invN = 1.0 / (double)N_NODES;
        double m0 = stats[0] * invN, m1 = stats[1] * invN;
        double e00 = stats[2] * invN, e11 = stats[3] * invN, e01 = stats[4] * invN;
        double a = w1[2 * c], b = w1[2 * c + 1], t = b1[c];
        double meanH = a * m0 + b * m1 + t;
        double eh2 = a * a * e00 + b * b * e11 + 2.0 * a * b * e01 +
                     2.0 * t * (a * m0 + b * m1) + t * t;
        double var = eh2 - meanH * meanH;
        double inv = 1.0 / sqrt(var + 1e-5);
        float sc = (float)((double)gamma[c] * inv);
        float shift = beta[c] - (float)meanH * sc;
        sA[c] = (float)a * sc;
        sB[c] = (float)b * sc;
        sC[c] = (float)t * sc + shift;
        // v[c] = (gcn_w^T wb^T)[c]
        float vc = 0.f;
        for (int j = 0; j < 32; j++) vc += wb[j] * gcn_w[j * 32 + c];
        sV[c] = vc;
        // b2 . v (reduce over first 32 lanes)
        float gb = b2[c] * vc;
        for (int off = 16; off; off >>= 1) gb += __shfl_down(gb, off, 32);
        if (c == 0) sGB = gb;
    }
    __syncthreads();
    if (threadIdx.x < 32) {
        // u[k] = sum_c v[c] * w2[c*32+k]
        float u = 0.f;
        for (int c = 0; c < 32; c++) u += sV[c] * w2[c * 32 + threadIdx.x];
        sU[threadIdx.x] = u;
    }
    __syncthreads();
    float alpha = prelu_a[0];
    int n = blockIdx.x * blockDim.x + threadIdx.x;
    if (n < N_NODES) {
        float2 xv = ((const float2*)x)[n];
        float g = sGB;
#pragma unroll
        for (int c = 0; c < 32; c++) {
            float hb = sA[c] * xv.x + sB[c] * xv.y + sC[c];
            float pc = hb >= 0.f ? hb : alpha * hb;
            g += pc * sU[c];
        }
        float di = rsqrtf(degf[n] + 1.0f);
        float gg = di * g;
        dinv[n] = di;
        gs[n] = gg;
        acc[n] = gg;  // self-loop term; finalize multiplies by dinv
    }
}

// ---- pass B: LDS-privatized scatter  acc[dst] += gs[src], 4 edges/thread/iter ----
__global__ __launch_bounds__(T_HIST, 8) void scatter_hist_kernel(
        const void* __restrict__ ei, const float* __restrict__ gs,
        float* __restrict__ acc) {
    __shared__ float hist[PART];
    bool is64 = detect_is64(ei);
    int p = blockIdx.x & (P_PARTS - 1);
    int slice = blockIdx.x >> 3;
    int base = p * PART;

    for (int i = threadIdx.x; i < PART; i += T_HIST) hist[i] = 0.f;
    __syncthreads();

    int e0 = slice * SLICE_E, e1 = e0 + SLICE_E;
    if (is64) {
        const long long* srcp = (const long long*)ei;
        const long long* dstp = srcp + N_EDGES;
        for (int e = e0 + threadIdx.x * 4; e < e1; e += T_HIST * 4) {
            longlong2 da = *(const longlong2*)(dstp + e);
            longlong2 db = *(const longlong2*)(dstp + e + 2);
            longlong2 sa = *(const longlong2*)(srcp + e);
            longlong2 sb = *(const longlong2*)(srcp + e + 2);
            unsigned l0 = (unsigned)((int)da.x - base);
            unsigned l1 = (unsigned)((int)da.y - base);
            unsigned l2 = (unsigned)((int)db.x - base);
            unsigned l3 = (unsigned)((int)db.y - base);
            if (l0 < PART) atomicAdd(&hist[l0], gs[(int)sa.x]);
            if (l1 < PART) atomicAdd(&hist[l1], gs[(int)sa.y]);
            if (l2 < PART) atomicAdd(&hist[l2], gs[(int)sb.x]);
            if (l3 < PART) atomicAdd(&hist[l3], gs[(int)sb.y]);
        }
    } else {
        const int* srcp = (const int*)ei;
        const int* dstp = srcp + N_EDGES;
        for (int e = e0 + threadIdx.x * 4; e < e1; e += T_HIST * 4) {
            int4 d4 = *(const int4*)(dstp + e);
            int4 s4 = *(const int4*)(srcp + e);
            unsigned l0 = (unsigned)(d4.x - base);
            unsigned l1 = (unsigned)(d4.y - base);
            unsigned l2 = (unsigned)(d4.z - base);
            unsigned l3 = (unsigned)(d4.w - base);
            if (l0 < PART) atomicAdd(&hist[l0], gs[s4.x]);
            if (l1 < PART) atomicAdd(&hist[l1], gs[s4.y]);
            if (l2 < PART) atomicAdd(&hist[l2], gs[s4.z]);
            if (l3 < PART) atomicAdd(&hist[l3], gs[s4.w]);
        }
    }
    __syncthreads();
    for (int i = threadIdx.x; i < PART; i += T_HIST) {
        float v = hist[i];
        if (v != 0.f) unsafeAtomicAdd(&acc[base + i], v);
    }
}

// ---- finalize: out = dinv*acc + const ----
__global__ void finalize_kernel(const float* __restrict__ dinv, const float* __restrict__ acc,
                                const float* __restrict__ gcn_b, const float* __restrict__ wb,
                                const float* __restrict__ bb, float* __restrict__ out) {
    __shared__ float scc;
    if (threadIdx.x < 32) {
        float pv = wb[threadIdx.x] * gcn_b[threadIdx.x];
        for (int off = 16; off; off >>= 1) pv += __shfl_down(pv, off, 32);
        if (threadIdx.x == 0) scc = pv + bb[0];
    }
    __syncthreads();
    int n = blockIdx.x * blockDim.x + threadIdx.x;
    if (n < N_NODES) out[n] = dinv[n] * acc[n] + scc;
}

extern "C" void kernel_launch(void* const* d_in, const int* in_sizes, int n_in,
                              void* d_out, int out_size, void* d_ws, size_t ws_size,
                              hipStream_t stream) {
    const float* x       = (const float*)d_in[0];
    const void*  ei      = d_in[1];
    const float* w1      = (const float*)d_in[2];
    const float* b1      = (const float*)d_in[3];
    const float* bn_g    = (const float*)d_in[4];
    const float* bn_b    = (const float*)d_in[5];
    const float* prelu_a = (const float*)d_in[6];
    const float* w2      = (const float*)d_in[7];
    const float* b2      = (const float*)d_in[8];
    const float* gcn_w   = (const float*)d_in[9];
    const float* gcn_b   = (const float*)d_in[10];
    const float* wb      = (const float*)d_in[11];
    const float* bb      = (const float*)d_in[12];
    float* out = (float*)d_out;

    char* base = (char*)d_ws;
    double* stats = (double*)(base + OFF_STATS);
    float*  degf  = (float*)(base + OFF_DEG);
    float*  acc   = (float*)(base + OFF_ACC);
    float*  dinv  = (float*)(base + OFF_DINV);
    float*  gs    = (float*)(base + OFF_GS);

    // zero stats + degf (acc is fully initialized by encoder)
    hipMemsetAsync(d_ws, 0, OFF_DEG + PART * P_PARTS * 4, stream);

    deg_stats_kernel<<<BLOCKS_H, T_HIST, 0, stream>>>(x, ei, stats, degf);
    encoder_kernel<<<(N_NODES + 255) / 256, 256, 0, stream>>>(
        x, stats, w1, b1, bn_g, bn_b, prelu_a, w2, b2, gcn_w, wb, degf, dinv, gs, acc);
    scatter_hist_kernel<<<BLOCKS_H, T_HIST, 0, stream>>>(ei, gs, acc);
    finalize_kernel<<<(N_NODES + 255) / 256, 256, 0, stream>>>(dinv, acc, gcn_b, wb, bb, out);
}